// Round 4
// baseline (1291.324 us; speedup 1.0000x reference)
//
#include <hip/hip_runtime.h>
#include <hip/hip_bf16.h>
#include <math.h>

#define N_TOK 8192
#define C_EMB 1024
#define H_MOE 2048
#define NRUT  7

typedef __attribute__((ext_vector_type(8))) short bf16x8;
typedef __attribute__((ext_vector_type(4))) float f32x4;

__device__ __forceinline__ void gload_lds16(const void* gsrc, void* ldst) {
  __builtin_amdgcn_global_load_lds(
      (const __attribute__((address_space(1))) unsigned int*)gsrc,
      (__attribute__((address_space(3))) unsigned int*)ldst, 16, 0, 0);
}

__device__ __forceinline__ unsigned short f2bf(float f) {
  __hip_bfloat16 h = __float2bfloat16(f);
  return *reinterpret_cast<unsigned short*>(&h);
}

// ---------------- routing + x->bf16 ----------------
// grid 2048 x 256: one wave per token
__global__ __launch_bounds__(256) void routing_kernel(
    const float* __restrict__ x, const float* __restrict__ gw,
    const float* __restrict__ bias,
    unsigned short* __restrict__ xb, int* __restrict__ top1,
    int* __restrict__ pos, float* __restrict__ gate,
    int* __restrict__ counts, float* __restrict__ aux) {
  int wid = threadIdx.x >> 6, lane = threadIdx.x & 63;
  int t = blockIdx.x * 4 + wid;
  const float* xrow = x + (size_t)t * C_EMB;
  double acc[NRUT];
#pragma unroll
  for (int e = 0; e < NRUT; ++e) acc[e] = 0.0;
  for (int j = 0; j < C_EMB / 64; ++j) {
    float xv = xrow[j * 64 + lane];
    xb[(size_t)t * C_EMB + j * 64 + lane] = f2bf(xv);
#pragma unroll
    for (int e = 0; e < NRUT; ++e)
      acc[e] += (double)xv * (double)gw[e * C_EMB + j * 64 + lane];
  }
#pragma unroll
  for (int e = 0; e < NRUT; ++e)
    for (int s = 32; s; s >>= 1) acc[e] += __shfl_xor(acc[e], s);
  if (lane == 0) {
    double mx = acc[0];
#pragma unroll
    for (int e = 1; e < NRUT; ++e) mx = acc[e] > mx ? acc[e] : mx;
    double p[NRUT], den = 0.0;
#pragma unroll
    for (int e = 0; e < NRUT; ++e) { p[e] = exp(acc[e] - mx); den += p[e]; }
    int best = 0; double bp = -1e300;
#pragma unroll
    for (int e = 0; e < NRUT; ++e) {
      double pb = p[e] / den + (double)bias[e];
      if (pb > bp) { bp = pb; best = e; }
    }
    top1[t] = best;
    gate[t] = (float)(p[best] / den);
    pos[t] = atomicAdd(&counts[best], 1);
  }
  if (blockIdx.x == 0 && threadIdx.x == 0) aux[0] = 0.0f;
}

__global__ void offsets_kernel(const int* __restrict__ counts, int* __restrict__ offs) {
  if (threadIdx.x == 0) {
    int s = 0;
    for (int e = 0; e < NRUT; ++e) { offs[e] = s; s += counts[e]; }
    offs[NRUT] = s;
  }
}

__global__ __launch_bounds__(256) void scatter_kernel(
    const int* __restrict__ top1, const int* __restrict__ pos,
    const int* __restrict__ offs, int* __restrict__ perm) {
  int t = blockIdx.x * 256 + threadIdx.x;
  perm[offs[top1[t]] + pos[t]] = t;
}

// ---------------- transpose + fp32->bf16 convert ----------------
// in: [R][C] fp32 ; out: [slot][C][R] bf16. z==0 -> shared (slot 7), z>=1 -> routed z-1
__global__ __launch_bounds__(256) void transconv_kernel(
    const float* __restrict__ sw, const float* __restrict__ rw,
    unsigned short* __restrict__ out, int R, int C) {
  int z = blockIdx.z;
  int slot = (z == 0) ? NRUT : z - 1;
  const float* src = (z == 0) ? sw : rw + (size_t)(z - 1) * R * C;
  unsigned short* dst = out + (size_t)slot * R * C;
  __shared__ float tile[32][33];
  int c0 = blockIdx.x * 32, r0 = blockIdx.y * 32;
  int tx = threadIdx.x & 31, ty = threadIdx.x >> 5;  // ty in 0..7
#pragma unroll
  for (int i = 0; i < 4; ++i)
    tile[ty + i * 8][tx] = src[(size_t)(r0 + ty + i * 8) * C + c0 + tx];
  __syncthreads();
#pragma unroll
  for (int i = 0; i < 4; ++i)
    dst[(size_t)(c0 + ty + i * 8) * R + r0 + tx] = f2bf(tile[tx][ty + i * 8]);
}

// ---------------- fused up+gate GEMM with SwiGLU ----------------
// grid (64 mtiles, 16 npanels, 8 experts[7=shared]), block 256 (4 waves)
#define BM 128
#define BN 128
#define BK 32

__global__ __launch_bounds__(256) void up_kernel(
    const unsigned short* __restrict__ xb,   // [8192][1024]
    const unsigned short* __restrict__ WGT,  // [8][2048][1024] (n-major)
    const unsigned short* __restrict__ WUT,  // [8][2048][1024]
    const int* __restrict__ counts, const int* __restrict__ offs,
    const int* __restrict__ perm,
    unsigned short* __restrict__ act_r,      // [8192][2048]
    unsigned short* __restrict__ act_s) {    // [8192][2048]
  int e = blockIdx.z;
  bool shared_e = (e == NRUT);
  int count = shared_e ? N_TOK : counts[e];
  int base  = shared_e ? 0 : offs[e];
  int mt = blockIdx.x, np = blockIdx.y;
  if (mt * BM >= count) return;

  __shared__ __align__(16) unsigned short As[BM * BK];
  __shared__ __align__(16) unsigned short Bg[BN * BK];
  __shared__ __align__(16) unsigned short Bu[BN * BK];

  int tid = threadIdx.x, wid = tid >> 6, lane = tid & 63;
  const unsigned short* wg = WGT + ((size_t)e << 21);
  const unsigned short* wu = WUT + ((size_t)e << 21);

  int r0t = wid * 16 + (lane >> 2);        // chunk rows
  int r1t = (wid + 4) * 16 + (lane >> 2);
  int acol = (lane & 3) * 8;

  auto rowtok = [&](int r) -> int {
    int p = mt * BM + r;
    if (p >= count) p = count - 1;
    return shared_e ? p : perm[base + p];
  };
  size_t asrc0 = (size_t)rowtok(r0t) * C_EMB + acol;
  size_t asrc1 = (size_t)rowtok(r1t) * C_EMB + acol;
  size_t bsrc0 = (size_t)(np * BN + r0t) * C_EMB + acol;
  size_t bsrc1 = (size_t)(np * BN + r1t) * C_EMB + acol;

  f32x4 accg[4][4] = {};
  f32x4 accu[4][4] = {};

  int wr = wid >> 1, wc = wid & 1;
  int afoff = (wr * 64 + (lane & 15)) * BK + (lane >> 4) * 8;
  int bfoff = (wc * 64 + (lane & 15)) * BK + (lane >> 4) * 8;

  for (int kt = 0; kt < C_EMB / BK; ++kt) {
    __syncthreads();
    gload_lds16(xb + asrc0 + kt * BK, (void*)&As[wid * 512]);
    gload_lds16(xb + asrc1 + kt * BK, (void*)&As[(wid + 4) * 512]);
    gload_lds16(wg + bsrc0 + kt * BK, (void*)&Bg[wid * 512]);
    gload_lds16(wg + bsrc1 + kt * BK, (void*)&Bg[(wid + 4) * 512]);
    gload_lds16(wu + bsrc0 + kt * BK, (void*)&Bu[wid * 512]);
    gload_lds16(wu + bsrc1 + kt * BK, (void*)&Bu[(wid + 4) * 512]);
    __syncthreads();
    bf16x8 a[4], bg[4], bu[4];
#pragma unroll
    for (int i = 0; i < 4; ++i) {
      a[i]  = *(const bf16x8*)&As[afoff + i * 16 * BK];
      bg[i] = *(const bf16x8*)&Bg[bfoff + i * 16 * BK];
      bu[i] = *(const bf16x8*)&Bu[bfoff + i * 16 * BK];
    }
#pragma unroll
    for (int mi = 0; mi < 4; ++mi)
#pragma unroll
      for (int ni = 0; ni < 4; ++ni) {
        accg[mi][ni] = __builtin_amdgcn_mfma_f32_16x16x32_bf16(a[mi], bg[ni], accg[mi][ni], 0, 0, 0);
        accu[mi][ni] = __builtin_amdgcn_mfma_f32_16x16x32_bf16(a[mi], bu[ni], accu[mi][ni], 0, 0, 0);
      }
  }

  unsigned short* act = shared_e ? act_s : act_r;
#pragma unroll
  for (int mi = 0; mi < 4; ++mi)
#pragma unroll
    for (int ni = 0; ni < 4; ++ni) {
      int row0 = mt * BM + wr * 64 + mi * 16 + ((lane >> 4) << 2);
      int col = np * BN + wc * 64 + ni * 16 + (lane & 15);
#pragma unroll
      for (int r = 0; r < 4; ++r) {
        int rr = row0 + r;
        if (rr < count) {
          float g = accg[mi][ni][r], u = accu[mi][ni][r];
          float a_ = (g / (1.0f + __expf(-g))) * u;
          act[(size_t)(base + rr) * H_MOE + col] = f2bf(a_);
        }
      }
    }
}

// ---------------- down GEMM ----------------
// grid (64 mtiles, 8 npanels, E) ; ROUTED: E=7 RMW, else E=1 plain store
template <bool ROUTED>
__global__ __launch_bounds__(256) void down_kernel(
    const unsigned short* __restrict__ act,  // [8192][2048]
    const unsigned short* __restrict__ WDT,  // [8][1024][2048] (n-major)
    const int* __restrict__ counts, const int* __restrict__ offs,
    const int* __restrict__ perm, const float* __restrict__ gate,
    float* __restrict__ y) {
  int e = ROUTED ? blockIdx.z : NRUT;
  int count = ROUTED ? counts[e] : N_TOK;
  int base  = ROUTED ? offs[e] : 0;
  int mt = blockIdx.x, np = blockIdx.y;
  if (mt * BM >= count) return;

  __shared__ __align__(16) unsigned short As[BM * BK];
  __shared__ __align__(16) unsigned short Bs[BN * BK];

  int tid = threadIdx.x, wid = tid >> 6, lane = tid & 63;
  const unsigned short* wd = WDT + ((size_t)e << 21);

  int r0t = wid * 16 + (lane >> 2);
  int r1t = (wid + 4) * 16 + (lane >> 2);
  int acol = (lane & 3) * 8;

  int p0 = mt * BM + r0t; if (p0 >= count) p0 = count - 1;
  int p1 = mt * BM + r1t; if (p1 >= count) p1 = count - 1;
  size_t asrc0 = (size_t)(base + p0) * H_MOE + acol;
  size_t asrc1 = (size_t)(base + p1) * H_MOE + acol;
  size_t bsrc0 = (size_t)(np * BN + r0t) * H_MOE + acol;
  size_t bsrc1 = (size_t)(np * BN + r1t) * H_MOE + acol;

  f32x4 acc[4][4] = {};
  int wr = wid >> 1, wc = wid & 1;
  int afoff = (wr * 64 + (lane & 15)) * BK + (lane >> 4) * 8;
  int bfoff = (wc * 64 + (lane & 15)) * BK + (lane >> 4) * 8;

  for (int kt = 0; kt < H_MOE / BK; ++kt) {
    __syncthreads();
    gload_lds16(act + asrc0 + kt * BK, (void*)&As[wid * 512]);
    gload_lds16(act + asrc1 + kt * BK, (void*)&As[(wid + 4) * 512]);
    gload_lds16(wd + bsrc0 + kt * BK, (void*)&Bs[wid * 512]);
    gload_lds16(wd + bsrc1 + kt * BK, (void*)&Bs[(wid + 4) * 512]);
    __syncthreads();
    bf16x8 a[4], b[4];
#pragma unroll
    for (int i = 0; i < 4; ++i) {
      a[i] = *(const bf16x8*)&As[afoff + i * 16 * BK];
      b[i] = *(const bf16x8*)&Bs[bfoff + i * 16 * BK];
    }
#pragma unroll
    for (int mi = 0; mi < 4; ++mi)
#pragma unroll
      for (int ni = 0; ni < 4; ++ni)
        acc[mi][ni] = __builtin_amdgcn_mfma_f32_16x16x32_bf16(a[mi], b[ni], acc[mi][ni], 0, 0, 0);
  }

#pragma unroll
  for (int mi = 0; mi < 4; ++mi)
#pragma unroll
    for (int ni = 0; ni < 4; ++ni) {
      int prow0 = mt * BM + wr * 64 + mi * 16 + ((lane >> 4) << 2);
      int col = np * BN + wc * 64 + ni * 16 + (lane & 15);
#pragma unroll
      for (int r = 0; r < 4; ++r) {
        int p = prow0 + r;
        if (p < count) {
          float v = acc[mi][ni][r];
          if (ROUTED) {
            int tok = perm[base + p];
            y[(size_t)tok * C_EMB + col] += gate[tok] * v;
          } else {
            y[(size_t)p * C_EMB + col] = v;
          }
        }
      }
    }
}

// ---------------- launch ----------------
extern "C" void kernel_launch(void* const* d_in, const int* in_sizes, int n_in,
                              void* d_out, int out_size, void* d_ws, size_t ws_size,
                              hipStream_t stream) {
  const float* x        = (const float*)d_in[0];
  const float* gate_w   = (const float*)d_in[1];
  const float* exp_bias = (const float*)d_in[2];
  const float* s_wg     = (const float*)d_in[3];
  const float* s_wu     = (const float*)d_in[4];
  const float* s_wd     = (const float*)d_in[5];
  const float* r_wg     = (const float*)d_in[6];
  const float* r_wu     = (const float*)d_in[7];
  const float* r_wd     = (const float*)d_in[8];

  float* y   = (float*)d_out;
  float* aux = y + (size_t)N_TOK * C_EMB;

  char* w = (char*)d_ws;
  unsigned short* xb  = (unsigned short*)w; w += (size_t)N_TOK * C_EMB * 2;
  unsigned short* WGT = (unsigned short*)w; w += (size_t)8 * H_MOE * C_EMB * 2;
  unsigned short* WUT = (unsigned short*)w; w += (size_t)8 * H_MOE * C_EMB * 2;
  unsigned short* WDT = (unsigned short*)w; w += (size_t)8 * C_EMB * H_MOE * 2;
  unsigned short* act_s = (unsigned short*)w; w += (size_t)N_TOK * H_MOE * 2;
  unsigned short* act_r = (unsigned short*)w; w += (size_t)N_TOK * H_MOE * 2;
  int*   top1  = (int*)w; w += N_TOK * 4;
  int*   pos   = (int*)w; w += N_TOK * 4;
  int*   perm  = (int*)w; w += N_TOK * 4;
  float* gate  = (float*)w; w += N_TOK * 4;
  int*   counts = (int*)w; w += 8 * 4;
  int*   offs   = (int*)w; w += 8 * 4;

  hipMemsetAsync(counts, 0, 8 * 4, stream);

  routing_kernel<<<N_TOK / 4, 256, 0, stream>>>(x, gate_w, exp_bias, xb, top1,
                                                pos, gate, counts, aux);
  offsets_kernel<<<1, 64, 0, stream>>>(counts, offs);
  scatter_kernel<<<N_TOK / 256, 256, 0, stream>>>(top1, pos, offs, perm);

  // wg/wu: in [1024][2048] -> out [2048][1024]
  transconv_kernel<<<dim3(H_MOE / 32, C_EMB / 32, 8), 256, 0, stream>>>(
      s_wg, r_wg, WGT, C_EMB, H_MOE);
  transconv_kernel<<<dim3(H_MOE / 32, C_EMB / 32, 8), 256, 0, stream>>>(
      s_wu, r_wu, WUT, C_EMB, H_MOE);
  // wd: in [2048][1024] -> out [1024][2048]
  transconv_kernel<<<dim3(C_EMB / 32, H_MOE / 32, 8), 256, 0, stream>>>(
      s_wd, r_wd, WDT, H_MOE, C_EMB);

  up_kernel<<<dim3(N_TOK / BM, H_MOE / BN, 8), 256, 0, stream>>>(
      xb, WGT, WUT, counts, offs, perm, act_r, act_s);

  down_kernel<false><<<dim3(N_TOK / BM, C_EMB / BN, 1), 256, 0, stream>>>(
      act_s, WDT, counts, offs, perm, gate, y);
  down_kernel<true><<<dim3(N_TOK / BM, C_EMB / BN, NRUT), 256, 0, stream>>>(
      act_r, WDT, counts, offs, perm, gate, y);
}

// Round 5
// 776.467 us; speedup vs baseline: 1.6631x; 1.6631x over previous
//
#include <hip/hip_runtime.h>
#include <hip/hip_bf16.h>
#include <math.h>

#define N_TOK 8192
#define C_EMB 1024
#define H_MOE 2048
#define NRUT  7

typedef __attribute__((ext_vector_type(8))) short bf16x8;
typedef __attribute__((ext_vector_type(4))) float f32x4;

__device__ __forceinline__ void gload_lds16(const void* gsrc, void* ldst) {
  __builtin_amdgcn_global_load_lds(
      (const __attribute__((address_space(1))) unsigned int*)gsrc,
      (__attribute__((address_space(3))) unsigned int*)ldst, 16, 0, 0);
}

__device__ __forceinline__ unsigned short f2bf(float f) {
  __hip_bfloat16 h = __float2bfloat16(f);
  return *reinterpret_cast<unsigned short*>(&h);
}

// ---------------- routing + x->bf16 ----------------
__global__ __launch_bounds__(256) void routing_kernel(
    const float* __restrict__ x, const float* __restrict__ gw,
    const float* __restrict__ bias,
    unsigned short* __restrict__ xb, int* __restrict__ top1,
    int* __restrict__ pos, float* __restrict__ gate,
    int* __restrict__ counts, float* __restrict__ aux) {
  int wid = threadIdx.x >> 6, lane = threadIdx.x & 63;
  int t = blockIdx.x * 4 + wid;
  const float* xrow = x + (size_t)t * C_EMB;
  double acc[NRUT];
#pragma unroll
  for (int e = 0; e < NRUT; ++e) acc[e] = 0.0;
  for (int j = 0; j < C_EMB / 64; ++j) {
    float xv = xrow[j * 64 + lane];
    xb[(size_t)t * C_EMB + j * 64 + lane] = f2bf(xv);
#pragma unroll
    for (int e = 0; e < NRUT; ++e)
      acc[e] += (double)xv * (double)gw[e * C_EMB + j * 64 + lane];
  }
#pragma unroll
  for (int e = 0; e < NRUT; ++e)
    for (int s = 32; s; s >>= 1) acc[e] += __shfl_xor(acc[e], s);
  if (lane == 0) {
    double mx = acc[0];
#pragma unroll
    for (int e = 1; e < NRUT; ++e) mx = acc[e] > mx ? acc[e] : mx;
    double p[NRUT], den = 0.0;
#pragma unroll
    for (int e = 0; e < NRUT; ++e) { p[e] = exp(acc[e] - mx); den += p[e]; }
    int best = 0; double bp = -1e300;
#pragma unroll
    for (int e = 0; e < NRUT; ++e) {
      double pb = p[e] / den + (double)bias[e];
      if (pb > bp) { bp = pb; best = e; }
    }
    top1[t] = best;
    gate[t] = (float)(p[best] / den);
    pos[t] = atomicAdd(&counts[best], 1);
  }
  if (blockIdx.x == 0 && threadIdx.x == 0) aux[0] = 0.0f;
}

__global__ void offsets_kernel(const int* __restrict__ counts, int* __restrict__ offs) {
  if (threadIdx.x == 0) {
    int s = 0;
    for (int e = 0; e < NRUT; ++e) { offs[e] = s; s += counts[e]; }
    offs[NRUT] = s;
  }
}

__global__ __launch_bounds__(256) void scatter_kernel(
    const int* __restrict__ top1, const int* __restrict__ pos,
    const int* __restrict__ offs, int* __restrict__ perm) {
  int t = blockIdx.x * 256 + threadIdx.x;
  perm[offs[top1[t]] + pos[t]] = t;
}

// ---------------- transpose + fp32->bf16 convert ----------------
__global__ __launch_bounds__(256) void transconv_kernel(
    const float* __restrict__ sw, const float* __restrict__ rw,
    unsigned short* __restrict__ out, int R, int C) {
  int z = blockIdx.z;
  int slot = (z == 0) ? NRUT : z - 1;
  const float* src = (z == 0) ? sw : rw + (size_t)(z - 1) * R * C;
  unsigned short* dst = out + (size_t)slot * R * C;
  __shared__ float tile[32][33];
  int c0 = blockIdx.x * 32, r0 = blockIdx.y * 32;
  int tx = threadIdx.x & 31, ty = threadIdx.x >> 5;
#pragma unroll
  for (int i = 0; i < 4; ++i)
    tile[ty + i * 8][tx] = src[(size_t)(r0 + ty + i * 8) * C + c0 + tx];
  __syncthreads();
#pragma unroll
  for (int i = 0; i < 4; ++i)
    dst[(size_t)(c0 + ty + i * 8) * R + r0 + tx] = f2bf(tile[tx][ty + i * 8]);
}

// ---------------- fused up+gate GEMM with SwiGLU (2-phase prefetch) ----------------
#define BM 128
#define BN 128
#define BK 32

__global__ __launch_bounds__(256) void up_kernel(
    const unsigned short* __restrict__ xb,   // [8192][1024]
    const unsigned short* __restrict__ WGT,  // [8][2048][1024] (n-major)
    const unsigned short* __restrict__ WUT,  // [8][2048][1024]
    const int* __restrict__ counts, const int* __restrict__ offs,
    const int* __restrict__ perm,
    unsigned short* __restrict__ act_r,      // [8192][2048]
    unsigned short* __restrict__ act_s) {    // [8192][2048]
  int e = blockIdx.z;
  bool shared_e = (e == NRUT);
  int count = shared_e ? N_TOK : counts[e];
  int base  = shared_e ? 0 : offs[e];
  // XCD swizzle: XCD = blockIdx.x % 8; cluster same-np blocks on one XCD
  int gx = blockIdx.x, gy = blockIdx.y;
  int np = (gx & 7) | ((gy & 1) << 3);     // 0..15
  int mt = (gx >> 3) | ((gy >> 1) << 3);   // 0..63
  if (mt * BM >= count) return;

  __shared__ __align__(16) unsigned short As[2][BM * BK];
  __shared__ __align__(16) unsigned short Bg[2][BN * BK];
  __shared__ __align__(16) unsigned short Bu[2][BN * BK];

  int tid = threadIdx.x, wid = tid >> 6, lane = tid & 63;
  const unsigned short* wg = WGT + ((size_t)e << 21);
  const unsigned short* wu = WUT + ((size_t)e << 21);

  int r0t = wid * 16 + (lane >> 2);        // staging rows
  int r1t = (wid + 4) * 16 + (lane >> 2);
  int acol = (lane & 3) * 8;

  auto rowtok = [&](int r) -> int {
    int p = mt * BM + r;
    if (p >= count) p = count - 1;
    return shared_e ? p : perm[base + p];
  };
  size_t asrc0 = (size_t)rowtok(r0t) * C_EMB + acol;
  size_t asrc1 = (size_t)rowtok(r1t) * C_EMB + acol;
  size_t bsrc0 = (size_t)(np * BN + r0t) * C_EMB + acol;
  size_t bsrc1 = (size_t)(np * BN + r1t) * C_EMB + acol;

  f32x4 accg[4][4] = {};
  f32x4 accu[4][4] = {};

  int wr = wid >> 1, wc = wid & 1;
  int afoff = (wr * 64 + (lane & 15)) * BK + (lane >> 4) * 8;
  int bfoff = (wc * 64 + (lane & 15)) * BK + (lane >> 4) * 8;

  auto stage = [&](int buf, int kt) {
    gload_lds16(xb + asrc0 + kt * BK, (void*)&As[buf][wid * 512]);
    gload_lds16(xb + asrc1 + kt * BK, (void*)&As[buf][(wid + 4) * 512]);
    gload_lds16(wg + bsrc0 + kt * BK, (void*)&Bg[buf][wid * 512]);
    gload_lds16(wg + bsrc1 + kt * BK, (void*)&Bg[buf][(wid + 4) * 512]);
    gload_lds16(wu + bsrc0 + kt * BK, (void*)&Bu[buf][wid * 512]);
    gload_lds16(wu + bsrc1 + kt * BK, (void*)&Bu[buf][(wid + 4) * 512]);
  };

  const int NT = C_EMB / BK;
  stage(0, 0);
  for (int kt = 0; kt < NT; ++kt) {
    int cur = kt & 1;
    __syncthreads();  // drains vmcnt: buf[cur] staged (prev iter) is ready
    if (kt + 1 < NT) stage(cur ^ 1, kt + 1);  // overlaps with compute below
    bf16x8 a[4], bg[4], bu[4];
#pragma unroll
    for (int i = 0; i < 4; ++i) {
      a[i]  = *(const bf16x8*)&As[cur][afoff + i * 16 * BK];
      bg[i] = *(const bf16x8*)&Bg[cur][bfoff + i * 16 * BK];
      bu[i] = *(const bf16x8*)&Bu[cur][bfoff + i * 16 * BK];
    }
#pragma unroll
    for (int mi = 0; mi < 4; ++mi)
#pragma unroll
      for (int ni = 0; ni < 4; ++ni) {
        accg[mi][ni] = __builtin_amdgcn_mfma_f32_16x16x32_bf16(a[mi], bg[ni], accg[mi][ni], 0, 0, 0);
        accu[mi][ni] = __builtin_amdgcn_mfma_f32_16x16x32_bf16(a[mi], bu[ni], accu[mi][ni], 0, 0, 0);
      }
  }

  unsigned short* act = shared_e ? act_s : act_r;
#pragma unroll
  for (int mi = 0; mi < 4; ++mi)
#pragma unroll
    for (int ni = 0; ni < 4; ++ni) {
      int row0 = mt * BM + wr * 64 + mi * 16 + ((lane >> 4) << 2);
      int col = np * BN + wc * 64 + ni * 16 + (lane & 15);
#pragma unroll
      for (int r = 0; r < 4; ++r) {
        int rr = row0 + r;
        if (rr < count) {
          float g = accg[mi][ni][r], u = accu[mi][ni][r];
          float a_ = (g / (1.0f + __expf(-g))) * u;
          act[(size_t)(base + rr) * H_MOE + col] = f2bf(a_);
        }
      }
    }
}

// ---------------- down GEMM (2-phase prefetch) ----------------
template <bool ROUTED>
__global__ __launch_bounds__(256) void down_kernel(
    const unsigned short* __restrict__ act,  // [8192][2048]
    const unsigned short* __restrict__ WDT,  // [8][1024][2048] (n-major)
    const int* __restrict__ counts, const int* __restrict__ offs,
    const int* __restrict__ perm, const float* __restrict__ gate,
    float* __restrict__ y) {
  int e = ROUTED ? blockIdx.z : NRUT;
  int count = ROUTED ? counts[e] : N_TOK;
  int base  = ROUTED ? offs[e] : 0;
  // XCD swizzle: each XCD owns one np panel
  int gx = blockIdx.x, gy = blockIdx.y;
  int np = gx & 7;                 // 0..7
  int mt = (gx >> 3) | (gy << 3);  // 0..63
  if (mt * BM >= count) return;

  __shared__ __align__(16) unsigned short As[2][BM * BK];
  __shared__ __align__(16) unsigned short Bs[2][BN * BK];

  int tid = threadIdx.x, wid = tid >> 6, lane = tid & 63;
  const unsigned short* wd = WDT + ((size_t)e << 21);

  int r0t = wid * 16 + (lane >> 2);
  int r1t = (wid + 4) * 16 + (lane >> 2);
  int acol = (lane & 3) * 8;

  int p0 = mt * BM + r0t; if (p0 >= count) p0 = count - 1;
  int p1 = mt * BM + r1t; if (p1 >= count) p1 = count - 1;
  size_t asrc0 = (size_t)(base + p0) * H_MOE + acol;
  size_t asrc1 = (size_t)(base + p1) * H_MOE + acol;
  size_t bsrc0 = (size_t)(np * BN + r0t) * H_MOE + acol;
  size_t bsrc1 = (size_t)(np * BN + r1t) * H_MOE + acol;

  f32x4 acc[4][4] = {};
  int wr = wid >> 1, wc = wid & 1;
  int afoff = (wr * 64 + (lane & 15)) * BK + (lane >> 4) * 8;
  int bfoff = (wc * 64 + (lane & 15)) * BK + (lane >> 4) * 8;

  auto stage = [&](int buf, int kt) {
    gload_lds16(act + asrc0 + kt * BK, (void*)&As[buf][wid * 512]);
    gload_lds16(act + asrc1 + kt * BK, (void*)&As[buf][(wid + 4) * 512]);
    gload_lds16(wd + bsrc0 + kt * BK, (void*)&Bs[buf][wid * 512]);
    gload_lds16(wd + bsrc1 + kt * BK, (void*)&Bs[buf][(wid + 4) * 512]);
  };

  const int NT = H_MOE / BK;
  stage(0, 0);
  for (int kt = 0; kt < NT; ++kt) {
    int cur = kt & 1;
    __syncthreads();
    if (kt + 1 < NT) stage(cur ^ 1, kt + 1);
    bf16x8 a[4], b[4];
#pragma unroll
    for (int i = 0; i < 4; ++i) {
      a[i] = *(const bf16x8*)&As[cur][afoff + i * 16 * BK];
      b[i] = *(const bf16x8*)&Bs[cur][bfoff + i * 16 * BK];
    }
#pragma unroll
    for (int mi = 0; mi < 4; ++mi)
#pragma unroll
      for (int ni = 0; ni < 4; ++ni)
        acc[mi][ni] = __builtin_amdgcn_mfma_f32_16x16x32_bf16(a[mi], b[ni], acc[mi][ni], 0, 0, 0);
  }

#pragma unroll
  for (int mi = 0; mi < 4; ++mi)
#pragma unroll
    for (int ni = 0; ni < 4; ++ni) {
      int prow0 = mt * BM + wr * 64 + mi * 16 + ((lane >> 4) << 2);
      int col = np * BN + wc * 64 + ni * 16 + (lane & 15);
#pragma unroll
      for (int r = 0; r < 4; ++r) {
        int p = prow0 + r;
        if (p < count) {
          float v = acc[mi][ni][r];
          if (ROUTED) {
            int tok = perm[base + p];
            y[(size_t)tok * C_EMB + col] += gate[tok] * v;
          } else {
            y[(size_t)p * C_EMB + col] = v;
          }
        }
      }
    }
}

// ---------------- launch ----------------
extern "C" void kernel_launch(void* const* d_in, const int* in_sizes, int n_in,
                              void* d_out, int out_size, void* d_ws, size_t ws_size,
                              hipStream_t stream) {
  const float* x        = (const float*)d_in[0];
  const float* gate_w   = (const float*)d_in[1];
  const float* exp_bias = (const float*)d_in[2];
  const float* s_wg     = (const float*)d_in[3];
  const float* s_wu     = (const float*)d_in[4];
  const float* s_wd     = (const float*)d_in[5];
  const float* r_wg     = (const float*)d_in[6];
  const float* r_wu     = (const float*)d_in[7];
  const float* r_wd     = (const float*)d_in[8];

  float* y   = (float*)d_out;
  float* aux = y + (size_t)N_TOK * C_EMB;

  char* w = (char*)d_ws;
  unsigned short* xb  = (unsigned short*)w; w += (size_t)N_TOK * C_EMB * 2;
  unsigned short* WGT = (unsigned short*)w; w += (size_t)8 * H_MOE * C_EMB * 2;
  unsigned short* WUT = (unsigned short*)w; w += (size_t)8 * H_MOE * C_EMB * 2;
  unsigned short* WDT = (unsigned short*)w; w += (size_t)8 * C_EMB * H_MOE * 2;
  unsigned short* act_s = (unsigned short*)w; w += (size_t)N_TOK * H_MOE * 2;
  unsigned short* act_r = (unsigned short*)w; w += (size_t)N_TOK * H_MOE * 2;
  int*   top1  = (int*)w; w += N_TOK * 4;
  int*   pos   = (int*)w; w += N_TOK * 4;
  int*   perm  = (int*)w; w += N_TOK * 4;
  float* gate  = (float*)w; w += N_TOK * 4;
  int*   counts = (int*)w; w += 8 * 4;
  int*   offs   = (int*)w; w += 8 * 4;

  hipMemsetAsync(counts, 0, 8 * 4, stream);

  routing_kernel<<<N_TOK / 4, 256, 0, stream>>>(x, gate_w, exp_bias, xb, top1,
                                                pos, gate, counts, aux);
  offsets_kernel<<<1, 64, 0, stream>>>(counts, offs);
  scatter_kernel<<<N_TOK / 256, 256, 0, stream>>>(top1, pos, offs, perm);

  transconv_kernel<<<dim3(H_MOE / 32, C_EMB / 32, 8), 256, 0, stream>>>(
      s_wg, r_wg, WGT, C_EMB, H_MOE);
  transconv_kernel<<<dim3(H_MOE / 32, C_EMB / 32, 8), 256, 0, stream>>>(
      s_wu, r_wu, WUT, C_EMB, H_MOE);
  transconv_kernel<<<dim3(C_EMB / 32, H_MOE / 32, 8), 256, 0, stream>>>(
      s_wd, r_wd, WDT, H_MOE, C_EMB);

  up_kernel<<<dim3(N_TOK / BM, H_MOE / BN, 8), 256, 0, stream>>>(
      xb, WGT, WUT, counts, offs, perm, act_r, act_s);

  down_kernel<false><<<dim3(N_TOK / BM, C_EMB / BN, 1), 256, 0, stream>>>(
      act_s, WDT, counts, offs, perm, gate, y);
  down_kernel<true><<<dim3(N_TOK / BM, C_EMB / BN, NRUT), 256, 0, stream>>>(
      act_r, WDT, counts, offs, perm, gate, y);
}